// Round 19
// baseline (106.773 us; speedup 1.0000x reference)
//
#include <hip/hip_runtime.h>
#include <hip/hip_fp16.h>
#include <cstdint>

// ---------------- workspace layout (bytes) ----------------
// xt2: fp16 chunked-NHWC texture [b][kc=8][4096 px][128 ch] = 16.78 MB
static constexpr size_t OFF_XT   = 0;
static constexpr size_t OFF_HIAL = 16777216;                            // fp16 hi_al [b][c][hw] 16.78 MB
static constexpr size_t OFF_PART = OFF_HIAL;                            // ALIAS: part [72][b][28][4096] fp16 (33.03 MB)
                                                                        // safe: k_sum consumes part before k_dcn writes hial
static constexpr size_t OFF_MU   = OFF_HIAL + 33554432;                 // uint4 meta [b][9][4096]: fp16 w x4, i16 slot x4
static constexpr size_t OFF_WA   = OFF_MU  + 2ull*9*4096*16;            // fp16 waT [9][8kc][4ks][2mt][16col][4kg] uint4 granules
static constexpr size_t OFF_WB   = OFF_WA  + 36864ull*16;               // fp16 wB [32g][9p][32o][32i] u32-packed (dcn)
static constexpr size_t OFF_SUM  = OFF_WB  + 147456ull*4;               // f32 sums [3][b][9][4096] = 884,736 B
// end ~= 52 MB

using f16x8 = __attribute__((ext_vector_type(8))) _Float16;
typedef __attribute__((ext_vector_type(4))) float f32x4;
typedef __attribute__((ext_vector_type(2))) float f32x2;

__device__ __forceinline__ uint16_t f2h(float f) { return __half_as_ushort(__float2half(f)); }
__device__ __forceinline__ __half2 u2h(uint32_t u) { union { uint32_t u; __half2 h; } x; x.u = u; return x.h; }
__device__ __forceinline__ uint32_t h2u(__half2 h) { union { uint32_t u; __half2 h; } x; x.h = h; return x.u; }

// bilinear blend with fp16 weights
__device__ __forceinline__ f16x8 blend4h(uint4 A, uint4 B, uint4 C, uint4 D,
                                         __half2 wab, __half2 wcd) {
    __half2 h00 = __half2half2(__low2half(wab));
    __half2 h01 = __half2half2(__high2half(wab));
    __half2 h10 = __half2half2(__low2half(wcd));
    __half2 h11 = __half2half2(__high2half(wcd));
    const uint32_t* a = (const uint32_t*)&A;
    const uint32_t* b = (const uint32_t*)&B;
    const uint32_t* c = (const uint32_t*)&C;
    const uint32_t* d = (const uint32_t*)&D;
    union { uint32_t u[4]; f16x8 v; } r;
#pragma unroll
    for (int e = 0; e < 4; ++e) {
        __half2 acc = __hmul2(h00, u2h(a[e]));
        acc = __hfma2(h01, u2h(b[e]), acc);
        acc = __hfma2(h10, u2h(c[e]), acc);
        acc = __hfma2(h11, u2h(d[e]), acc);
        r.u[e] = h2u(acc);
    }
    return r.v;
}

// ---------------- prep: both weight transposes in one dispatch ----------------
__global__ void k_prep(const float* __restrict__ w_off, const float* __restrict__ w_dcn,
                       uint4* __restrict__ waT, uint32_t* __restrict__ wb) {
    int idx = blockIdx.x * 256 + threadIdx.x;              // 36864 + 147456
    if (idx < 36864) {
        int kg = idx & 3, col = (idx >> 2) & 15, mt = (idx >> 6) & 1;
        int ks = (idx >> 7) & 3, kc = (idx >> 9) & 7, p = idx >> 12;
        int oc = mt * 16 + col;
        int chb = kc * 128 + ks * 32 + kg * 8;
        union { uint32_t u[4]; uint4 v; } r;
#pragma unroll
        for (int e = 0; e < 4; ++e) {
            uint32_t lo = 0, hi = 0;
            if (oc < 27) {
                lo = f2h(w_off[(size_t)oc * 9216 + (size_t)(chb + 2 * e) * 9 + p]);
                hi = f2h(w_off[(size_t)oc * 9216 + (size_t)(chb + 2 * e + 1) * 9 + p]);
            }
            r.u[e] = lo | (hi << 16);
        }
        waT[idx] = r.v;
    } else {
        int j = idx - 36864;                    // 32*9*32*16
        if (j >= 32 * 9 * 32 * 16) return;
        int g = j / (9 * 32 * 16), r = j % (9 * 32 * 16);
        int p = r / (32 * 16), r2 = r % (32 * 16), o = r2 / 16, ip = r2 % 16;
        uint32_t lo = f2h(w_dcn[((size_t)(g * 32 + o) * 32 + 2 * ip) * 9 + p]);
        uint32_t hi = f2h(w_dcn[((size_t)(g * 32 + o) * 32 + 2 * ip + 1) * 9 + p]);
        wb[j] = lo | (hi << 16);
    }
}

// ---------------- K0: hi_res NCHW f32 -> chunked-NHWC fp16 xt2[b][kc][px][128ch] ----------------
__global__ void k_transpose(const float* __restrict__ x, uint32_t* __restrict__ xt) {
    __shared__ float tile[64][65];
    int cblk = blockIdx.x * 64, y = blockIdx.y, b = blockIdx.z, t = threadIdx.x;
    const float* src = x + ((size_t)(b * 1024 + cblk)) * 4096 + y * 64;
#pragma unroll
    for (int k = 0; k < 16; ++k) {
        int lin = t + k * 256;
        int cl = lin >> 6, xx = lin & 63;
        tile[cl][xx] = src[(size_t)cl * 4096 + xx];
    }
    __syncthreads();
    int kc = cblk >> 7, half = (cblk & 64) >> 1;           // u32 offset within 128-ch chunk
    uint32_t* dst = xt + ((size_t)(b * 8 + kc) * 4096 + (size_t)y * 64) * 64 + half;
#pragma unroll
    for (int k = 0; k < 8; ++k) {
        int lin = t + k * 256;
        int xx = lin >> 5, cp = lin & 31;
        uint32_t lo = f2h(tile[2 * cp][xx]);
        uint32_t hi = f2h(tile[2 * cp + 1][xx]);
        dst[(size_t)xx * 64 + cp] = lo | (hi << 16);
    }
}

// ---------------- K1: offset conv via MFMA + LDS-staged tile, 8-way K-split ----------------
// launch_bounds(256,6): 6 blocks/CU (153 KB LDS) -- the r16 8-way split was capped at 4
// by launch_bounds(256,4); grid 2048 now actually reaches 24 waves/CU.
__global__ __launch_bounds__(256, 6) void k_offconv_mfma(const uint32_t* __restrict__ xt,
                                                         const uint4* __restrict__ waT,
                                                         __half* __restrict__ part) {
    __shared__ uint4 sb[1632];                 // 102 slots * 16 granules = 25.5 KB
    int bx = blockIdx.x;                       // 0..127
    int y = bx >> 1, xh = bx & 1;
    int kc = blockIdx.y, b = blockIdx.z;
    int t = threadIdx.x, wave = t >> 6, lane = t & 63;
    int pxg = wave >> 1, mt = wave & 1;
    int col = lane & 15, kg = lane >> 4;

    {
        const uint32_t* srcb = xt + ((size_t)(b * 8 + kc) * 4096) * 64;
#pragma unroll
        for (int i = 0; i < 7; ++i) {
            int idx = i * 256 + t;
            if (idx < 1632) {
                int s = idx >> 4, q = idx & 15;
                int rr = s >= 68 ? 2 : (s >= 34 ? 1 : 0);
                int pxl = s - rr * 34;
                int gy = y - 1 + rr, gx = xh * 32 - 1 + pxl;
                uint4 val = uint4{0, 0, 0, 0};
                if (gy >= 0 && gy < 64 && gx >= 0 && gx < 64)
                    val = *(const uint4*)(srcb + ((size_t)(gy * 64 + gx)) * 64 + q * 4);
                sb[s * 16 + (q ^ (s & 15))] = val;
            }
        }
    }
    __syncthreads();

    f32x4 acc[9];
#pragma unroll
    for (int p = 0; p < 9; ++p) acc[p] = f32x4{0.f, 0.f, 0.f, 0.f};

#pragma unroll
    for (int p = 0; p < 9; ++p) {
        int ky = p / 3 - 1, kx = p % 3 - 1;
        int pxl = pxg * 16 + col + kx + 1;
        int s = (ky + 1) * 34 + pxl;
#pragma unroll
        for (int ks = 0; ks < 4; ++ks) {
            f16x8 bfr = *(const f16x8*)&sb[s * 16 + ((ks * 4 + kg) ^ (s & 15))];
            int gidx = ((((p * 8 + kc) * 4 + ks) * 2 + mt) * 16 + col) * 4 + kg;
            f16x8 afr = *(const f16x8*)&waT[gidx];
            acc[p] = __builtin_amdgcn_mfma_f32_16x16x32_f16(afr, bfr, acc[p], 0, 0, 0);
        }
    }

    int px = y * 64 + xh * 32 + pxg * 16 + col;
    int ocl = mt * 16 + kg * 4;                 // first oc of this lane's 4
#pragma unroll
    for (int p = 0; p < 9; ++p) {
        __half* pc = part + ((size_t)((kc * 9 + p) * 2 + b)) * 28 * 4096 + px;
#pragma unroll
        for (int j = 0; j < 4; ++j)
            if (ocl + j < 28) pc[(size_t)(ocl + j) * 4096] = __float2half(acc[p][j]);
    }
}

// ---------------- K2a: sum 72 fp16 partials per stream (dy/dx/m) -> f32 ----------------
__global__ void k_sum(const __half* __restrict__ part, float* __restrict__ sums) {
    int idx = blockIdx.x * 256 + threadIdx.x;              // 3*2*9*4096 = 221184
    if (idx >= 221184) return;
    int st = idx / 73728, r = idx % 73728;                 // r = b*36864 + p*4096 + hw
    int b = r / 36864, r2 = r % 36864;
    const __half* pb = part + (size_t)b * 28 * 4096 + (size_t)st * 36864 + r2;
    float s = 0.f;
#pragma unroll 8
    for (int si = 0; si < 72; ++si)
        s += __half2float(pb[(size_t)si * 229376]);        // 2*28*4096 per s-step
    sums[idx] = s;
}

// ---------------- K2b: sums -> compact sampling meta ----------------
__global__ void k_meta2(const float* __restrict__ sums, const float* __restrict__ b_off,
                        uint4* __restrict__ mu) {
    int idx = blockIdx.x * 256 + threadIdx.x;              // 2*9*4096
    if (idx >= 2 * 9 * 4096) return;
    int b = idx / (9 * 4096), r = idx % (9 * 4096), p = r / 4096, hw = r % 4096;
    int h = hw >> 6, w = hw & 63;
    float sdy = b_off[p]      + sums[idx];
    float sdx = b_off[p + 9]  + sums[73728 + idx];
    float sm  = b_off[p + 18] + sums[147456 + idx];
    float m = 1.f / (1.f + expf(-sm));
    int ky = p / 3 - 1, kx = p % 3 - 1;
    float sy = (float)(h + ky) + sdy;
    float sx = (float)(w + kx) + sdx;
    float y0f = floorf(sy), x0f = floorf(sx);
    float wy = sy - y0f, wx = sx - x0f;
    int y0 = (int)fminf(fmaxf(y0f, -2.f), 64.f);
    int x0 = (int)fminf(fmaxf(x0f, -2.f), 64.f);
    bool vy0 = (y0 >= 0) && (y0 < 64), vy1 = (y0 + 1 >= 0) && (y0 + 1 < 64);
    bool vx0 = (x0 >= 0) && (x0 < 64), vx1 = (x0 + 1 >= 0) && (x0 + 1 < 64);
    float w00 = (1.f - wy) * (1.f - wx) * m * ((vy0 && vx0) ? 1.f : 0.f);
    float w01 = (1.f - wy) * wx         * m * ((vy0 && vx1) ? 1.f : 0.f);
    float w10 = wy * (1.f - wx)         * m * ((vy1 && vx0) ? 1.f : 0.f);
    float w11 = wy * wx                 * m * ((vy1 && vx1) ? 1.f : 0.f);
    int cy0 = min(max(y0, 0), 63),     cx0 = min(max(x0, 0), 63);
    int cy1 = min(max(y0 + 1, 0), 63), cx1 = min(max(x0 + 1, 0), 63);
    int blo = (h >> 3) * 8 - 6;
    blo = blo < 0 ? 0 : (blo > 44 ? 44 : blo);
    int blo64 = blo * 64;
    int s0 = cy0 * 64 + cx0 - blo64, s1 = cy0 * 64 + cx1 - blo64;
    int s2 = cy1 * 64 + cx0 - blo64, s3 = cy1 * 64 + cx1 - blo64;
    uint32_t wlo = (uint32_t)f2h(w00) | ((uint32_t)f2h(w01) << 16);
    uint32_t whi = (uint32_t)f2h(w10) | ((uint32_t)f2h(w11) << 16);
    uint32_t ilo = ((uint32_t)(uint16_t)(short)s0) | (((uint32_t)(uint16_t)(short)s1) << 16);
    uint32_t ihi = ((uint32_t)(uint16_t)(short)s2) | (((uint32_t)(uint16_t)(short)s3) << 16);
    mu[idx] = uint4{wlo, whi, ilo, ihi};
}

// ---------------- K3: deformable sample + grouped conv, LDS-staged texture ----------------
__global__ __launch_bounds__(512, 4) void k_dcn_lds(const uint32_t* __restrict__ xt,
                                                    const uint32_t* __restrict__ wb,
                                                    const uint4* __restrict__ mu,
                                                    const float* __restrict__ b_dcn,
                                                    __half* __restrict__ hial) {
    __shared__ uint4 ldsq[5120];               // 20 rows * 64 px * 64 B = 80 KB
    int g = blockIdx.x, band = blockIdx.y, b = blockIdx.z;
    int y0 = band * 8;
    int band_lo = y0 - 6;
    if (band_lo < 0) band_lo = 0;
    if (band_lo > 44) band_lo = 44;
    int t = threadIdx.x;

    {
        const uint32_t* src = xt + ((size_t)(b * 8 + (g >> 2)) * 4096 + (size_t)band_lo * 64) * 64 + (g & 3) * 16;
#pragma unroll
        for (int i = 0; i < 10; ++i) {
            int Q = i * 512 + t;
            int s = Q >> 2;
            int q = (Q & 3) ^ ((s >> 1) & 3);
            ldsq[Q] = *(const uint4*)(src + (size_t)s * 64 + q * 4);
        }
    }
    __syncthreads();
    const uint32_t* ldsb = (const uint32_t*)ldsq;

    int wave = t >> 6, lane = t & 63;
    int col = lane & 15, kg = lane >> 4;
    int strip = (wave & 3) * 16;               // x-strip of 16 px
    int rbase = (wave >> 2) * 4;               // rows rbase..rbase+3 of the band
    const uint32_t* xb = xt + ((size_t)(b * 8 + (g >> 2)) * 4096) * 64 + (g & 3) * 16 + kg * 4;
    const uint32_t* wg = wb + (size_t)g * 9 * 32 * 16 + col * 16 + kg * 4;
    const uint4* mub = mu + (size_t)b * 9 * 4096;
    const float* bd  = b_dcn + g * 32;
    int blo64 = band_lo * 64;

#define LDSRD(SS) (*(const uint4*)(ldsb + (SS) * 16 + ((kg ^ (((SS) >> 1) & 3)) << 2)))
#define GSLOW(SS, U)                                                               \
    {                                                                              \
        int s_ = (SS);                                                             \
        int sc_ = s_ < 0 ? 0 : (s_ > 1279 ? 1279 : s_);                            \
        U = LDSRD(sc_);                                                            \
        if ((unsigned)s_ >= 1280u)                                                 \
            U = *(const uint4*)(xb + (size_t)(s_ + blo64) * 64);                   \
    }

    for (int r = 0; r < 4; ++r) {
        int pix = (y0 + rbase + r) * 64 + strip + col;
        f32x4 acc0 = {0.f, 0.f, 0.f, 0.f};
        f32x4 acc1 = {0.f, 0.f, 0.f, 0.f};
#pragma unroll
        for (int p = 0; p < 9; ++p) {
            uint4 cm = mub[p * 4096 + pix];
            int s0 = (short)(cm.z & 0xffffu), s1 = (short)(cm.z >> 16);
            int s2 = (short)(cm.w & 0xffffu), s3 = (short)(cm.w >> 16);
            unsigned mx = (unsigned)s0;
            mx = mx > (unsigned)s1 ? mx : (unsigned)s1;
            mx = mx > (unsigned)s2 ? mx : (unsigned)s2;
            mx = mx > (unsigned)s3 ? mx : (unsigned)s3;
            uint4 u0, u1, u2, u3;
            if (__builtin_expect(mx >= 1280u, 0)) {
                GSLOW(s0, u0)
                GSLOW(s1, u1)
                GSLOW(s2, u2)
                GSLOW(s3, u3)
            } else {
                u0 = LDSRD(s0);
                u1 = LDSRD(s1);
                u2 = LDSRD(s2);
                u3 = LDSRD(s3);
            }
            f16x8 bfr = blend4h(u0, u1, u2, u3, u2h(cm.x), u2h(cm.y));
            const uint32_t* ap = wg + (size_t)p * 512;
            f16x8 af0 = *(const f16x8*)ap;
            f16x8 af1 = *(const f16x8*)(ap + 256);
            acc0 = __builtin_amdgcn_mfma_f32_16x16x32_f16(af0, bfr, acc0, 0, 0, 0);
            acc1 = __builtin_amdgcn_mfma_f32_16x16x32_f16(af1, bfr, acc1, 0, 0, 0);
        }
        __half* pc = hial + ((size_t)b * 1024 + g * 32) * 4096 + pix;
#pragma unroll
        for (int j = 0; j < 4; ++j) {
            pc[(size_t)(kg * 4 + j) * 4096]      = __float2half(acc0[j] + bd[kg * 4 + j]);
            pc[(size_t)(16 + kg * 4 + j) * 4096] = __float2half(acc1[j] + bd[16 + kg * 4 + j]);
        }
    }
#undef LDSRD
#undef GSLOW
}

// ---------------- K4: fused upsample + grouped 1x1 conv (fp16 hial, NT stores) ----------------
__global__ __launch_bounds__(256, 4) void k_post5(const float* __restrict__ lo,
                                                  const __half* __restrict__ hial,
                                                  const float* __restrict__ wp,
                                                  const float* __restrict__ bp,
                                                  float* __restrict__ out) {
    int gq = blockIdx.x, kq = blockIdx.y, b = blockIdx.z;
    int t = threadIdx.x;
    int g = __builtin_amdgcn_readfirstlane(gq * 4 + (t >> 6));
    int lane = t & 63, k = kq * 4 + (lane >> 4), w4 = lane & 15;
    int rm = k > 0 ? k - 1 : 0, rp = k < 31 ? k + 1 : 31;
    int lc = 2 * w4 - 1; lc = lc < 0 ? 0 : (lc > 28 ? 28 : lc);
    bool is0 = (w4 == 0), is15 = (w4 == 15);

    f32x4 acc0[8], acc1[8];
#pragma unroll
    for (int o = 0; o < 8; ++o) {
        float bv = bp[g * 8 + o];
        acc0[o] = f32x4{bv, bv, bv, bv};
        acc1[o] = acc0[o];
    }
    const float* wrow = wp + (size_t)g * 96;
    int cbase = g * 12;

#define UPROW(LB, R, H)                                                            \
    {                                                                              \
        f32x4 q = *(const f32x4*)((LB) + (R) * 32 + lc);                           \
        float e0 = is15 ? q.y : q.x;                                               \
        float p0 = is0 ? q.x : (is15 ? q.z : q.y);                                 \
        float p1 = is0 ? q.y : (is15 ? q.w : q.z);                                 \
        float e3 = is0 ? q.z : q.w;                                                \
        H = f32x4{0.25f * e0 + 0.75f * p0, 0.75f * p0 + 0.25f * p1,                \
                  0.25f * p0 + 0.75f * p1, 0.75f * p1 + 0.25f * e3};               \
    }
#define LOCH(I)                                                                    \
    {                                                                              \
        const float* lb = lo + ((size_t)(b * 2048 + cbase + (I))) * 1024;          \
        f32x4 hm, hk, hp;                                                          \
        UPROW(lb, rm, hm) UPROW(lb, k, hk) UPROW(lb, rp, hp)                       \
        f32x4 va = 0.25f * hm + 0.75f * hk;                                        \
        f32x4 vb = 0.75f * hk + 0.25f * hp;                                        \
        _Pragma("unroll")                                                          \
        for (int o = 0; o < 8; ++o) {                                              \
            float w = wrow[o * 12 + (I)];                                          \
            acc0[o] += w * va;                                                     \
            acc1[o] += w * vb;                                                     \
        }                                                                          \
    }
#define HICH(I)                                                                    \
    {                                                                              \
        const __half* hb = hial + ((size_t)(b * 1024 + cbase + (I) - 2048)) * 4096 \
                          + (size_t)(2 * k) * 64 + 4 * w4;                         \
        __half2 ha0 = *(const __half2*)(hb);                                       \
        __half2 ha1 = *(const __half2*)(hb + 2);                                   \
        __half2 hb0 = *(const __half2*)(hb + 64);                                  \
        __half2 hb1 = *(const __half2*)(hb + 66);                                  \
        f32x4 va = {__half2float(ha0.x), __half2float(ha0.y),                      \
                    __half2float(ha1.x), __half2float(ha1.y)};                     \
        f32x4 vb = {__half2float(hb0.x), __half2float(hb0.y),                      \
                    __half2float(hb1.x), __half2float(hb1.y)};                     \
        _Pragma("unroll")                                                          \
        for (int o = 0; o < 8; ++o) {                                              \
            float w = wrow[o * 12 + (I)];                                          \
            acc0[o] += w * va;                                                     \
            acc1[o] += w * vb;                                                     \
        }                                                                          \
    }

    if (g <= 169) {
#pragma unroll 4
        for (int i = 0; i < 12; ++i) LOCH(i)
    } else if (g >= 171) {
#pragma unroll 4
        for (int i = 0; i < 12; ++i) HICH(i)
    } else {
#pragma unroll 4
        for (int i = 0; i < 8; ++i) LOCH(i)
#pragma unroll
        for (int i = 8; i < 12; ++i) HICH(i)
    }
#undef LOCH
#undef HICH
#undef UPROW

    float* ob = out + ((size_t)(b * 2048 + g * 8)) * 4096 + (size_t)(2 * k) * 64 + 4 * w4;
#pragma unroll
    for (int o = 0; o < 8; ++o) {
        __builtin_nontemporal_store(acc0[o], (f32x4*)(ob + (size_t)o * 4096));
        __builtin_nontemporal_store(acc1[o], (f32x4*)(ob + (size_t)o * 4096 + 64));
    }
}

extern "C" void kernel_launch(void* const* d_in, const int* in_sizes, int n_in,
                              void* d_out, int out_size, void* d_ws, size_t ws_size,
                              hipStream_t stream) {
    const float* lo_res = (const float*)d_in[0];
    const float* hi_res = (const float*)d_in[1];
    const float* w_off  = (const float*)d_in[2];
    const float* b_off  = (const float*)d_in[3];
    const float* w_dcn  = (const float*)d_in[4];
    const float* b_dcn  = (const float*)d_in[5];
    const float* w_post = (const float*)d_in[6];
    const float* b_post = (const float*)d_in[7];
    float* out = (float*)d_out;
    char* ws = (char*)d_ws;

    uint32_t* xt  = (uint32_t*)(ws + OFF_XT);
    __half* hial  = (__half*)(ws + OFF_HIAL);
    __half* part  = (__half*)(ws + OFF_PART);    // aliases hial region (consumed before hial written)
    uint4* mup    = (uint4*)(ws + OFF_MU);
    uint4* waT    = (uint4*)(ws + OFF_WA);
    uint32_t* wbp = (uint32_t*)(ws + OFF_WB);
    float* sums   = (float*)(ws + OFF_SUM);

    k_prep<<<(36864 + 32 * 9 * 32 * 16 + 255) / 256, 256, 0, stream>>>(w_off, w_dcn, waT, wbp);
    k_transpose<<<dim3(16, 64, 2), 256, 0, stream>>>(hi_res, xt);
    k_offconv_mfma<<<dim3(128, 8, 2), 256, 0, stream>>>(xt, waT, part);
    k_sum<<<(221184 + 255) / 256, 256, 0, stream>>>(part, sums);
    k_meta2<<<(2 * 9 * 4096 + 255) / 256, 256, 0, stream>>>(sums, b_off, mup);
    k_dcn_lds<<<dim3(32, 8, 2), 512, 0, stream>>>(xt, wbp, mup, b_dcn, hial);
    k_post5<<<dim3(64, 8, 2), 256, 0, stream>>>(lo_res, hial, w_post, b_post, out);
}

// Round 20
// 105.587 us; speedup vs baseline: 1.0112x; 1.0112x over previous
//
#include <hip/hip_runtime.h>
#include <hip/hip_fp16.h>
#include <cstdint>

// ---------------- workspace layout (bytes) ----------------
// xt2: fp16 chunked-NHWC texture [b][kc=8][4096 px][128 ch] = 16.78 MB
static constexpr size_t OFF_XT   = 0;
static constexpr size_t OFF_HIAL = 16777216;                            // fp16 hi_al [b][c][hw] 16.78 MB
static constexpr size_t OFF_PART = OFF_HIAL;                            // ALIAS: part [36][b][28][4096] fp16 (16.5 MB)
                                                                        // safe: k_meta consumes part before k_dcn writes hial
static constexpr size_t OFF_MU   = OFF_HIAL + 33554432;                 // uint4 meta [b][9][4096]: fp16 w x4, i16 slot x4
static constexpr size_t OFF_WA   = OFF_MU  + 2ull*9*4096*16;            // fp16 waT [9][8kc][4ks][2mt][16col][4kg] uint4 granules
static constexpr size_t OFF_WB   = OFF_WA  + 36864ull*16;               // fp16 wB [32g][9p][32o][32i] u32-packed (dcn)
// end ~= 51 MB

using f16x8 = __attribute__((ext_vector_type(8))) _Float16;
typedef __attribute__((ext_vector_type(4))) float f32x4;
typedef __attribute__((ext_vector_type(2))) float f32x2;

__device__ __forceinline__ uint16_t f2h(float f) { return __half_as_ushort(__float2half(f)); }
__device__ __forceinline__ __half2 u2h(uint32_t u) { union { uint32_t u; __half2 h; } x; x.u = u; return x.h; }
__device__ __forceinline__ uint32_t h2u(__half2 h) { union { uint32_t u; __half2 h; } x; x.h = h; return x.u; }

// bilinear blend with fp16 weights
__device__ __forceinline__ f16x8 blend4h(uint4 A, uint4 B, uint4 C, uint4 D,
                                         __half2 wab, __half2 wcd) {
    __half2 h00 = __half2half2(__low2half(wab));
    __half2 h01 = __half2half2(__high2half(wab));
    __half2 h10 = __half2half2(__low2half(wcd));
    __half2 h11 = __half2half2(__high2half(wcd));
    const uint32_t* a = (const uint32_t*)&A;
    const uint32_t* b = (const uint32_t*)&B;
    const uint32_t* c = (const uint32_t*)&C;
    const uint32_t* d = (const uint32_t*)&D;
    union { uint32_t u[4]; f16x8 v; } r;
#pragma unroll
    for (int e = 0; e < 4; ++e) {
        __half2 acc = __hmul2(h00, u2h(a[e]));
        acc = __hfma2(h01, u2h(b[e]), acc);
        acc = __hfma2(h10, u2h(c[e]), acc);
        acc = __hfma2(h11, u2h(d[e]), acc);
        r.u[e] = h2u(acc);
    }
    return r.v;
}

// ---------------- prep: both weight transposes in one dispatch ----------------
__global__ void k_prep(const float* __restrict__ w_off, const float* __restrict__ w_dcn,
                       uint4* __restrict__ waT, uint32_t* __restrict__ wb) {
    int idx = blockIdx.x * 256 + threadIdx.x;              // 36864 + 147456
    if (idx < 36864) {
        int kg = idx & 3, col = (idx >> 2) & 15, mt = (idx >> 6) & 1;
        int ks = (idx >> 7) & 3, kc = (idx >> 9) & 7, p = idx >> 12;
        int oc = mt * 16 + col;
        int chb = kc * 128 + ks * 32 + kg * 8;
        union { uint32_t u[4]; uint4 v; } r;
#pragma unroll
        for (int e = 0; e < 4; ++e) {
            uint32_t lo = 0, hi = 0;
            if (oc < 27) {
                lo = f2h(w_off[(size_t)oc * 9216 + (size_t)(chb + 2 * e) * 9 + p]);
                hi = f2h(w_off[(size_t)oc * 9216 + (size_t)(chb + 2 * e + 1) * 9 + p]);
            }
            r.u[e] = lo | (hi << 16);
        }
        waT[idx] = r.v;
    } else {
        int j = idx - 36864;                    // 32*9*32*16
        if (j >= 32 * 9 * 32 * 16) return;
        int g = j / (9 * 32 * 16), r = j % (9 * 32 * 16);
        int p = r / (32 * 16), r2 = r % (32 * 16), o = r2 / 16, ip = r2 % 16;
        uint32_t lo = f2h(w_dcn[((size_t)(g * 32 + o) * 32 + 2 * ip) * 9 + p]);
        uint32_t hi = f2h(w_dcn[((size_t)(g * 32 + o) * 32 + 2 * ip + 1) * 9 + p]);
        wb[j] = lo | (hi << 16);
    }
}

// ---------------- K0: hi_res NCHW f32 -> chunked-NHWC fp16 xt2[b][kc][px][128ch] ----------------
__global__ void k_transpose(const float* __restrict__ x, uint32_t* __restrict__ xt) {
    __shared__ float tile[64][65];
    int cblk = blockIdx.x * 64, y = blockIdx.y, b = blockIdx.z, t = threadIdx.x;
    const float* src = x + ((size_t)(b * 1024 + cblk)) * 4096 + y * 64;
#pragma unroll
    for (int k = 0; k < 16; ++k) {
        int lin = t + k * 256;
        int cl = lin >> 6, xx = lin & 63;
        tile[cl][xx] = src[(size_t)cl * 4096 + xx];
    }
    __syncthreads();
    int kc = cblk >> 7, half = (cblk & 64) >> 1;           // u32 offset within 128-ch chunk
    uint32_t* dst = xt + ((size_t)(b * 8 + kc) * 4096 + (size_t)y * 64) * 64 + half;
#pragma unroll
    for (int k = 0; k < 8; ++k) {
        int lin = t + k * 256;
        int xx = lin >> 5, cp = lin & 31;
        uint32_t lo = f2h(tile[2 * cp][xx]);
        uint32_t hi = f2h(tile[2 * cp + 1][xx]);
        dst[(size_t)xx * 64 + cp] = lo | (hi << 16);
    }
}

// ---------------- K1: offset conv via MFMA + LDS tile, 4-way K-split + reg prefetch ----------------
__global__ __launch_bounds__(256, 4) void k_offconv_mfma(const uint32_t* __restrict__ xt,
                                                         const uint4* __restrict__ waT,
                                                         __half* __restrict__ part) {
    __shared__ uint4 sb[1632];                 // 102 slots * 16 granules = 25.5 KB
    int bx = blockIdx.x;                       // 0..127
    int y = bx >> 1, xh = bx & 1;
    int kh = blockIdx.y, b = blockIdx.z;
    int t = threadIdx.x, wave = t >> 6, lane = t & 63;
    int pxg = wave >> 1, mt = wave & 1;
    int col = lane & 15, kg = lane >> 4;

    f32x4 acc[9];
#pragma unroll
    for (int p = 0; p < 9; ++p) acc[p] = f32x4{0.f, 0.f, 0.f, 0.f};

    uint4 stg[7];
#define STAGE_LOAD(KC)                                                             \
    {                                                                              \
        const uint32_t* srcb = xt + ((size_t)(b * 8 + (KC)) * 4096) * 64;          \
        _Pragma("unroll")                                                          \
        for (int i = 0; i < 7; ++i) {                                              \
            int idx = i * 256 + t;                                                 \
            stg[i] = uint4{0, 0, 0, 0};                                            \
            if (idx < 1632) {                                                      \
                int s = idx >> 4, q = idx & 15;                                    \
                int rr = s >= 68 ? 2 : (s >= 34 ? 1 : 0);                          \
                int pxl = s - rr * 34;                                             \
                int gy = y - 1 + rr, gx = xh * 32 - 1 + pxl;                       \
                if (gy >= 0 && gy < 64 && gx >= 0 && gx < 64)                      \
                    stg[i] = *(const uint4*)(srcb + ((size_t)(gy * 64 + gx)) * 64 + q * 4); \
            }                                                                      \
        }                                                                          \
    }
#define STAGE_WRITE                                                                \
    {                                                                              \
        _Pragma("unroll")                                                          \
        for (int i = 0; i < 7; ++i) {                                              \
            int idx = i * 256 + t;                                                 \
            if (idx < 1632) {                                                      \
                int s = idx >> 4, q = idx & 15;                                    \
                sb[s * 16 + (q ^ (s & 15))] = stg[i];                              \
            }                                                                      \
        }                                                                          \
    }

    int kc0 = kh * 2;
    STAGE_LOAD(kc0)
#pragma unroll
    for (int c2 = 0; c2 < 2; ++c2) {
        int kc = kc0 + c2;
        STAGE_WRITE
        __syncthreads();
        if (c2 == 0) STAGE_LOAD(kc0 + 1)        // overlaps with compute below
#pragma unroll
        for (int p = 0; p < 9; ++p) {
            int ky = p / 3 - 1, kx = p % 3 - 1;
            int pxl = pxg * 16 + col + kx + 1;
            int s = (ky + 1) * 34 + pxl;
#pragma unroll
            for (int ks = 0; ks < 4; ++ks) {
                f16x8 bfr = *(const f16x8*)&sb[s * 16 + ((ks * 4 + kg) ^ (s & 15))];
                int gidx = ((((p * 8 + kc) * 4 + ks) * 2 + mt) * 16 + col) * 4 + kg;
                f16x8 afr = *(const f16x8*)&waT[gidx];
                acc[p] = __builtin_amdgcn_mfma_f32_16x16x32_f16(afr, bfr, acc[p], 0, 0, 0);
            }
        }
        __syncthreads();
    }
#undef STAGE_LOAD
#undef STAGE_WRITE

    int px = y * 64 + xh * 32 + pxg * 16 + col;
    int ocl = mt * 16 + kg * 4;                 // first oc of this lane's 4
#pragma unroll
    for (int p = 0; p < 9; ++p) {
        __half* pc = part + ((size_t)((kh * 9 + p) * 2 + b)) * 28 * 4096 + px;
#pragma unroll
        for (int j = 0; j < 4; ++j)
            if (ocl + j < 28) pc[(size_t)(ocl + j) * 4096] = __float2half(acc[p][j]);
    }
}

// ---------------- K2: reduce 36 fp16 partials -> compact sampling meta ----------------
__global__ void k_meta(const __half* __restrict__ part, const float* __restrict__ b_off,
                       uint4* __restrict__ mu) {
    int idx = blockIdx.x * 256 + threadIdx.x;              // 2*9*4096
    if (idx >= 2 * 9 * 4096) return;
    int b = idx / (9 * 4096), r = idx % (9 * 4096), p = r / 4096, hw = r % 4096;
    int h = hw >> 6, w = hw & 63;
    float sdy = b_off[p], sdx = b_off[p + 9], sm = b_off[p + 18];
#pragma unroll 4
    for (int s = 0; s < 36; ++s) {
        const __half* pb = part + ((size_t)(s * 2 + b)) * 28 * 4096 + hw;
        sdy += __half2float(pb[(size_t)p * 4096]);
        sdx += __half2float(pb[(size_t)(p + 9) * 4096]);
        sm  += __half2float(pb[(size_t)(p + 18) * 4096]);
    }
    float m = 1.f / (1.f + expf(-sm));
    int ky = p / 3 - 1, kx = p % 3 - 1;
    float sy = (float)(h + ky) + sdy;
    float sx = (float)(w + kx) + sdx;
    float y0f = floorf(sy), x0f = floorf(sx);
    float wy = sy - y0f, wx = sx - x0f;
    int y0 = (int)fminf(fmaxf(y0f, -2.f), 64.f);
    int x0 = (int)fminf(fmaxf(x0f, -2.f), 64.f);
    bool vy0 = (y0 >= 0) && (y0 < 64), vy1 = (y0 + 1 >= 0) && (y0 + 1 < 64);
    bool vx0 = (x0 >= 0) && (x0 < 64), vx1 = (x0 + 1 >= 0) && (x0 + 1 < 64);
    float w00 = (1.f - wy) * (1.f - wx) * m * ((vy0 && vx0) ? 1.f : 0.f);
    float w01 = (1.f - wy) * wx         * m * ((vy0 && vx1) ? 1.f : 0.f);
    float w10 = wy * (1.f - wx)         * m * ((vy1 && vx0) ? 1.f : 0.f);
    float w11 = wy * wx                 * m * ((vy1 && vx1) ? 1.f : 0.f);
    int cy0 = min(max(y0, 0), 63),     cx0 = min(max(x0, 0), 63);
    int cy1 = min(max(y0 + 1, 0), 63), cx1 = min(max(x0 + 1, 0), 63);
    int blo = (h >> 3) * 8 - 6;
    blo = blo < 0 ? 0 : (blo > 44 ? 44 : blo);
    int blo64 = blo * 64;
    int s0 = cy0 * 64 + cx0 - blo64, s1 = cy0 * 64 + cx1 - blo64;
    int s2 = cy1 * 64 + cx0 - blo64, s3 = cy1 * 64 + cx1 - blo64;
    uint32_t wlo = (uint32_t)f2h(w00) | ((uint32_t)f2h(w01) << 16);
    uint32_t whi = (uint32_t)f2h(w10) | ((uint32_t)f2h(w11) << 16);
    uint32_t ilo = ((uint32_t)(uint16_t)(short)s0) | (((uint32_t)(uint16_t)(short)s1) << 16);
    uint32_t ihi = ((uint32_t)(uint16_t)(short)s2) | (((uint32_t)(uint16_t)(short)s3) << 16);
    mu[idx] = uint4{wlo, whi, ilo, ihi};
}

// ---------------- K3: deformable sample + grouped conv, LDS-staged texture ----------------
// XCD-aware g-swizzle: gridX=32 (multiple of 8) => XCD = bx%8; g = (bx%8)*4 + bx/8 gives
// each XCD one kc chunk (4 groups) per batch -> band re-staging hits its private L2.
// s_setprio(1) around the MFMA pair (waves are barrier-free after staging -> T5 regime).
__global__ __launch_bounds__(512, 4) void k_dcn_lds(const uint32_t* __restrict__ xt,
                                                    const uint32_t* __restrict__ wb,
                                                    const uint4* __restrict__ mu,
                                                    const float* __restrict__ b_dcn,
                                                    __half* __restrict__ hial) {
    __shared__ uint4 ldsq[5120];               // 20 rows * 64 px * 64 B = 80 KB
    int bx = blockIdx.x;
    int g = (bx & 7) * 4 + (bx >> 3);          // bijective XCD-locality swizzle
    int band = blockIdx.y, b = blockIdx.z;
    int y0 = band * 8;
    int band_lo = y0 - 6;
    if (band_lo < 0) band_lo = 0;
    if (band_lo > 44) band_lo = 44;
    int t = threadIdx.x;

    {
        const uint32_t* src = xt + ((size_t)(b * 8 + (g >> 2)) * 4096 + (size_t)band_lo * 64) * 64 + (g & 3) * 16;
#pragma unroll
        for (int i = 0; i < 10; ++i) {
            int Q = i * 512 + t;
            int s = Q >> 2;
            int q = (Q & 3) ^ ((s >> 1) & 3);
            ldsq[Q] = *(const uint4*)(src + (size_t)s * 64 + q * 4);
        }
    }
    __syncthreads();
    const uint32_t* ldsb = (const uint32_t*)ldsq;

    int wave = t >> 6, lane = t & 63;
    int col = lane & 15, kg = lane >> 4;
    int strip = (wave & 3) * 16;               // x-strip of 16 px
    int rbase = (wave >> 2) * 4;               // rows rbase..rbase+3 of the band
    const uint32_t* xb = xt + ((size_t)(b * 8 + (g >> 2)) * 4096) * 64 + (g & 3) * 16 + kg * 4;
    const uint32_t* wg = wb + (size_t)g * 9 * 32 * 16 + col * 16 + kg * 4;
    const uint4* mub = mu + (size_t)b * 9 * 4096;
    const float* bd  = b_dcn + g * 32;
    int blo64 = band_lo * 64;

#define LDSRD(SS) (*(const uint4*)(ldsb + (SS) * 16 + ((kg ^ (((SS) >> 1) & 3)) << 2)))
#define GSLOW(SS, U)                                                               \
    {                                                                              \
        int s_ = (SS);                                                             \
        int sc_ = s_ < 0 ? 0 : (s_ > 1279 ? 1279 : s_);                            \
        U = LDSRD(sc_);                                                            \
        if ((unsigned)s_ >= 1280u)                                                 \
            U = *(const uint4*)(xb + (size_t)(s_ + blo64) * 64);                   \
    }

    for (int r = 0; r < 4; ++r) {
        int pix = (y0 + rbase + r) * 64 + strip + col;
        f32x4 acc0 = {0.f, 0.f, 0.f, 0.f};
        f32x4 acc1 = {0.f, 0.f, 0.f, 0.f};
#pragma unroll
        for (int p = 0; p < 9; ++p) {
            uint4 cm = mub[p * 4096 + pix];
            int s0 = (short)(cm.z & 0xffffu), s1 = (short)(cm.z >> 16);
            int s2 = (short)(cm.w & 0xffffu), s3 = (short)(cm.w >> 16);
            unsigned mx = (unsigned)s0;
            mx = mx > (unsigned)s1 ? mx : (unsigned)s1;
            mx = mx > (unsigned)s2 ? mx : (unsigned)s2;
            mx = mx > (unsigned)s3 ? mx : (unsigned)s3;
            uint4 u0, u1, u2, u3;
            if (__builtin_expect(mx >= 1280u, 0)) {
                GSLOW(s0, u0)
                GSLOW(s1, u1)
                GSLOW(s2, u2)
                GSLOW(s3, u3)
            } else {
                u0 = LDSRD(s0);
                u1 = LDSRD(s1);
                u2 = LDSRD(s2);
                u3 = LDSRD(s3);
            }
            f16x8 bfr = blend4h(u0, u1, u2, u3, u2h(cm.x), u2h(cm.y));
            const uint32_t* ap = wg + (size_t)p * 512;
            f16x8 af0 = *(const f16x8*)ap;
            f16x8 af1 = *(const f16x8*)(ap + 256);
            __builtin_amdgcn_s_setprio(1);
            acc0 = __builtin_amdgcn_mfma_f32_16x16x32_f16(af0, bfr, acc0, 0, 0, 0);
            acc1 = __builtin_amdgcn_mfma_f32_16x16x32_f16(af1, bfr, acc1, 0, 0, 0);
            __builtin_amdgcn_s_setprio(0);
        }
        __half* pc = hial + ((size_t)b * 1024 + g * 32) * 4096 + pix;
#pragma unroll
        for (int j = 0; j < 4; ++j) {
            pc[(size_t)(kg * 4 + j) * 4096]      = __float2half(acc0[j] + bd[kg * 4 + j]);
            pc[(size_t)(16 + kg * 4 + j) * 4096] = __float2half(acc1[j] + bd[16 + kg * 4 + j]);
        }
    }
#undef LDSRD
#undef GSLOW
}

// ---------------- K4: fused upsample + grouped 1x1 conv (fp16 hial, NT stores) ----------------
__global__ __launch_bounds__(256, 4) void k_post5(const float* __restrict__ lo,
                                                  const __half* __restrict__ hial,
                                                  const float* __restrict__ wp,
                                                  const float* __restrict__ bp,
                                                  float* __restrict__ out) {
    int gq = blockIdx.x, kq = blockIdx.y, b = blockIdx.z;
    int t = threadIdx.x;
    int g = __builtin_amdgcn_readfirstlane(gq * 4 + (t >> 6));
    int lane = t & 63, k = kq * 4 + (lane >> 4), w4 = lane & 15;
    int rm = k > 0 ? k - 1 : 0, rp = k < 31 ? k + 1 : 31;
    int lc = 2 * w4 - 1; lc = lc < 0 ? 0 : (lc > 28 ? 28 : lc);
    bool is0 = (w4 == 0), is15 = (w4 == 15);

    f32x4 acc0[8], acc1[8];
#pragma unroll
    for (int o = 0; o < 8; ++o) {
        float bv = bp[g * 8 + o];
        acc0[o] = f32x4{bv, bv, bv, bv};
        acc1[o] = acc0[o];
    }
    const float* wrow = wp + (size_t)g * 96;
    int cbase = g * 12;

#define UPROW(LB, R, H)                                                            \
    {                                                                              \
        f32x4 q = *(const f32x4*)((LB) + (R) * 32 + lc);                           \
        float e0 = is15 ? q.y : q.x;                                               \
        float p0 = is0 ? q.x : (is15 ? q.z : q.y);                                 \
        float p1 = is0 ? q.y : (is15 ? q.w : q.z);                                 \
        float e3 = is0 ? q.z : q.w;                                                \
        H = f32x4{0.25f * e0 + 0.75f * p0, 0.75f * p0 + 0.25f * p1,                \
                  0.25f * p0 + 0.75f * p1, 0.75f * p1 + 0.25f * e3};               \
    }
#define LOCH(I)                                                                    \
    {                                                                              \
        const float* lb = lo + ((size_t)(b * 2048 + cbase + (I))) * 1024;          \
        f32x4 hm, hk, hp;                                                          \
        UPROW(lb, rm, hm) UPROW(lb, k, hk) UPROW(lb, rp, hp)                       \
        f32x4 va = 0.25f * hm + 0.75f * hk;                                        \
        f32x4 vb = 0.75f * hk + 0.25f * hp;                                        \
        _Pragma("unroll")                                                          \
        for (int o = 0; o < 8; ++o) {                                              \
            float w = wrow[o * 12 + (I)];                                          \
            acc0[o] += w * va;                                                     \
            acc1[o] += w * vb;                                                     \
        }                                                                          \
    }
#define HICH(I)                                                                    \
    {                                                                              \
        const __half* hb = hial + ((size_t)(b * 1024 + cbase + (I) - 2048)) * 4096 \
                          + (size_t)(2 * k) * 64 + 4 * w4;                         \
        __half2 ha0 = *(const __half2*)(hb);                                       \
        __half2 ha1 = *(const __half2*)(hb + 2);                                   \
        __half2 hb0 = *(const __half2*)(hb + 64);                                  \
        __half2 hb1 = *(const __half2*)(hb + 66);                                  \
        f32x4 va = {__half2float(ha0.x), __half2float(ha0.y),                      \
                    __half2float(ha1.x), __half2float(ha1.y)};                     \
        f32x4 vb = {__half2float(hb0.x), __half2float(hb0.y),                      \
                    __half2float(hb1.x), __half2float(hb1.y)};                     \
        _Pragma("unroll")                                                          \
        for (int o = 0; o < 8; ++o) {                                              \
            float w = wrow[o * 12 + (I)];                                          \
            acc0[o] += w * va;                                                     \
            acc1[o] += w * vb;                                                     \
        }                                                                          \
    }

    if (g <= 169) {
#pragma unroll 4
        for (int i = 0; i < 12; ++i) LOCH(i)
    } else if (g >= 171) {
#pragma unroll 4
        for (int i = 0; i < 12; ++i) HICH(i)
    } else {
#pragma unroll 4
        for (int i = 0; i < 8; ++i) LOCH(i)
#pragma unroll
        for (int i = 8; i < 12; ++i) HICH(i)
    }
#undef LOCH
#undef HICH
#undef UPROW

    float* ob = out + ((size_t)(b * 2048 + g * 8)) * 4096 + (size_t)(2 * k) * 64 + 4 * w4;
#pragma unroll
    for (int o = 0; o < 8; ++o) {
        __builtin_nontemporal_store(acc0[o], (f32x4*)(ob + (size_t)o * 4096));
        __builtin_nontemporal_store(acc1[o], (f32x4*)(ob + (size_t)o * 4096 + 64));
    }
}

extern "C" void kernel_launch(void* const* d_in, const int* in_sizes, int n_in,
                              void* d_out, int out_size, void* d_ws, size_t ws_size,
                              hipStream_t stream) {
    const float* lo_res = (const float*)d_in[0];
    const float* hi_res = (const float*)d_in[1];
    const float* w_off  = (const float*)d_in[2];
    const float* b_off  = (const float*)d_in[3];
    const float* w_dcn  = (const float*)d_in[4];
    const float* b_dcn  = (const float*)d_in[5];
    const float* w_post = (const float*)d_in[6];
    const float* b_post = (const float*)d_in[7];
    float* out = (float*)d_out;
    char* ws = (char*)d_ws;

    uint32_t* xt  = (uint32_t*)(ws + OFF_XT);
    __half* hial  = (__half*)(ws + OFF_HIAL);
    __half* part  = (__half*)(ws + OFF_PART);    // aliases hial region (consumed before hial written)
    uint4* mup    = (uint4*)(ws + OFF_MU);
    uint4* waT    = (uint4*)(ws + OFF_WA);
    uint32_t* wbp = (uint32_t*)(ws + OFF_WB);

    k_prep<<<(36864 + 32 * 9 * 32 * 16 + 255) / 256, 256, 0, stream>>>(w_off, w_dcn, waT, wbp);
    k_transpose<<<dim3(16, 64, 2), 256, 0, stream>>>(hi_res, xt);
    k_offconv_mfma<<<dim3(128, 4, 2), 256, 0, stream>>>(xt, waT, part);
    k_meta<<<(2 * 9 * 4096 + 255) / 256, 256, 0, stream>>>(part, b_off, mup);
    k_dcn_lds<<<dim3(32, 8, 2), 512, 0, stream>>>(xt, wbp, mup, b_dcn, hial);
    k_post5<<<dim3(64, 8, 2), 256, 0, stream>>>(lo_res, hial, w_post, b_post, out);
}

// Round 21
// 99.613 us; speedup vs baseline: 1.0719x; 1.0600x over previous
//
#include <hip/hip_runtime.h>
#include <hip/hip_fp16.h>
#include <cstdint>

// ---------------- workspace layout (bytes) ----------------
// xt2: fp16 chunked-NHWC texture [b][kc=8][4096 px][128 ch] = 16.78 MB
static constexpr size_t OFF_XT   = 0;
static constexpr size_t OFF_HIAL = 16777216;                            // fp16 hi_al [b][c][hw] 16.78 MB
static constexpr size_t OFF_PART = OFF_HIAL;                            // ALIAS: part [36][b][28][4096] fp16 (16.5 MB)
                                                                        // safe: k_meta consumes part before k_dcn writes hial
static constexpr size_t OFF_MU   = OFF_HIAL + 33554432;                 // uint4 meta [b][9][4096]: fp16 w x4, i16 slot x4
static constexpr size_t OFF_WA   = OFF_MU  + 2ull*9*4096*16;            // fp16 waT [9][8kc][4ks][2mt][16col][4kg] uint4 granules
static constexpr size_t OFF_WB   = OFF_WA  + 36864ull*16;               // fp16 wB [32g][9p][32o][32i] u32-packed (dcn)
// end ~= 51 MB

using f16x8 = __attribute__((ext_vector_type(8))) _Float16;
typedef __attribute__((ext_vector_type(4))) float f32x4;
typedef __attribute__((ext_vector_type(2))) float f32x2;

__device__ __forceinline__ uint16_t f2h(float f) { return __half_as_ushort(__float2half(f)); }
__device__ __forceinline__ __half2 u2h(uint32_t u) { union { uint32_t u; __half2 h; } x; x.u = u; return x.h; }
__device__ __forceinline__ uint32_t h2u(__half2 h) { union { uint32_t u; __half2 h; } x; x.h = h; return x.u; }

// bilinear blend with fp16 weights
__device__ __forceinline__ f16x8 blend4h(uint4 A, uint4 B, uint4 C, uint4 D,
                                         __half2 wab, __half2 wcd) {
    __half2 h00 = __half2half2(__low2half(wab));
    __half2 h01 = __half2half2(__high2half(wab));
    __half2 h10 = __half2half2(__low2half(wcd));
    __half2 h11 = __half2half2(__high2half(wcd));
    const uint32_t* a = (const uint32_t*)&A;
    const uint32_t* b = (const uint32_t*)&B;
    const uint32_t* c = (const uint32_t*)&C;
    const uint32_t* d = (const uint32_t*)&D;
    union { uint32_t u[4]; f16x8 v; } r;
#pragma unroll
    for (int e = 0; e < 4; ++e) {
        __half2 acc = __hmul2(h00, u2h(a[e]));
        acc = __hfma2(h01, u2h(b[e]), acc);
        acc = __hfma2(h10, u2h(c[e]), acc);
        acc = __hfma2(h11, u2h(d[e]), acc);
        r.u[e] = h2u(acc);
    }
    return r.v;
}

// ---------------- prep: both weight transposes in one dispatch ----------------
__global__ void k_prep(const float* __restrict__ w_off, const float* __restrict__ w_dcn,
                       uint4* __restrict__ waT, uint32_t* __restrict__ wb) {
    int idx = blockIdx.x * 256 + threadIdx.x;              // 36864 + 147456
    if (idx < 36864) {
        int kg = idx & 3, col = (idx >> 2) & 15, mt = (idx >> 6) & 1;
        int ks = (idx >> 7) & 3, kc = (idx >> 9) & 7, p = idx >> 12;
        int oc = mt * 16 + col;
        int chb = kc * 128 + ks * 32 + kg * 8;
        union { uint32_t u[4]; uint4 v; } r;
#pragma unroll
        for (int e = 0; e < 4; ++e) {
            uint32_t lo = 0, hi = 0;
            if (oc < 27) {
                lo = f2h(w_off[(size_t)oc * 9216 + (size_t)(chb + 2 * e) * 9 + p]);
                hi = f2h(w_off[(size_t)oc * 9216 + (size_t)(chb + 2 * e + 1) * 9 + p]);
            }
            r.u[e] = lo | (hi << 16);
        }
        waT[idx] = r.v;
    } else {
        int j = idx - 36864;                    // 32*9*32*16
        if (j >= 32 * 9 * 32 * 16) return;
        int g = j / (9 * 32 * 16), r = j % (9 * 32 * 16);
        int p = r / (32 * 16), r2 = r % (32 * 16), o = r2 / 16, ip = r2 % 16;
        uint32_t lo = f2h(w_dcn[((size_t)(g * 32 + o) * 32 + 2 * ip) * 9 + p]);
        uint32_t hi = f2h(w_dcn[((size_t)(g * 32 + o) * 32 + 2 * ip + 1) * 9 + p]);
        wb[j] = lo | (hi << 16);
    }
}

// ---------------- K0: hi_res NCHW f32 -> chunked-NHWC fp16 xt2[b][kc][px][128ch] ----------------
__global__ void k_transpose(const float* __restrict__ x, uint32_t* __restrict__ xt) {
    __shared__ float tile[64][65];
    int cblk = blockIdx.x * 64, y = blockIdx.y, b = blockIdx.z, t = threadIdx.x;
    const float* src = x + ((size_t)(b * 1024 + cblk)) * 4096 + y * 64;
#pragma unroll
    for (int k = 0; k < 16; ++k) {
        int lin = t + k * 256;
        int cl = lin >> 6, xx = lin & 63;
        tile[cl][xx] = src[(size_t)cl * 4096 + xx];
    }
    __syncthreads();
    int kc = cblk >> 7, half = (cblk & 64) >> 1;           // u32 offset within 128-ch chunk
    uint32_t* dst = xt + ((size_t)(b * 8 + kc) * 4096 + (size_t)y * 64) * 64 + half;
#pragma unroll
    for (int k = 0; k < 8; ++k) {
        int lin = t + k * 256;
        int xx = lin >> 5, cp = lin & 31;
        uint32_t lo = f2h(tile[2 * cp][xx]);
        uint32_t hi = f2h(tile[2 * cp + 1][xx]);
        dst[(size_t)xx * 64 + cp] = lo | (hi << 16);
    }
}

// ---------------- K1: offset conv via MFMA + LDS tile, 4-way K-split + reg prefetch ----------------
__global__ __launch_bounds__(256, 4) void k_offconv_mfma(const uint32_t* __restrict__ xt,
                                                         const uint4* __restrict__ waT,
                                                         __half* __restrict__ part) {
    __shared__ uint4 sb[1632];                 // 102 slots * 16 granules = 25.5 KB
    int bx = blockIdx.x;                       // 0..127
    int y = bx >> 1, xh = bx & 1;
    int kh = blockIdx.y, b = blockIdx.z;
    int t = threadIdx.x, wave = t >> 6, lane = t & 63;
    int pxg = wave >> 1, mt = wave & 1;
    int col = lane & 15, kg = lane >> 4;

    f32x4 acc[9];
#pragma unroll
    for (int p = 0; p < 9; ++p) acc[p] = f32x4{0.f, 0.f, 0.f, 0.f};

    uint4 stg[7];
#define STAGE_LOAD(KC)                                                             \
    {                                                                              \
        const uint32_t* srcb = xt + ((size_t)(b * 8 + (KC)) * 4096) * 64;          \
        _Pragma("unroll")                                                          \
        for (int i = 0; i < 7; ++i) {                                              \
            int idx = i * 256 + t;                                                 \
            stg[i] = uint4{0, 0, 0, 0};                                            \
            if (idx < 1632) {                                                      \
                int s = idx >> 4, q = idx & 15;                                    \
                int rr = s >= 68 ? 2 : (s >= 34 ? 1 : 0);                          \
                int pxl = s - rr * 34;                                             \
                int gy = y - 1 + rr, gx = xh * 32 - 1 + pxl;                       \
                if (gy >= 0 && gy < 64 && gx >= 0 && gx < 64)                      \
                    stg[i] = *(const uint4*)(srcb + ((size_t)(gy * 64 + gx)) * 64 + q * 4); \
            }                                                                      \
        }                                                                          \
    }
#define STAGE_WRITE                                                                \
    {                                                                              \
        _Pragma("unroll")                                                          \
        for (int i = 0; i < 7; ++i) {                                              \
            int idx = i * 256 + t;                                                 \
            if (idx < 1632) {                                                      \
                int s = idx >> 4, q = idx & 15;                                    \
                sb[s * 16 + (q ^ (s & 15))] = stg[i];                              \
            }                                                                      \
        }                                                                          \
    }

    int kc0 = kh * 2;
    STAGE_LOAD(kc0)
#pragma unroll
    for (int c2 = 0; c2 < 2; ++c2) {
        int kc = kc0 + c2;
        STAGE_WRITE
        __syncthreads();
        if (c2 == 0) STAGE_LOAD(kc0 + 1)        // overlaps with compute below
#pragma unroll
        for (int p = 0; p < 9; ++p) {
            int ky = p / 3 - 1, kx = p % 3 - 1;
            int pxl = pxg * 16 + col + kx + 1;
            int s = (ky + 1) * 34 + pxl;
#pragma unroll
            for (int ks = 0; ks < 4; ++ks) {
                f16x8 bfr = *(const f16x8*)&sb[s * 16 + ((ks * 4 + kg) ^ (s & 15))];
                int gidx = ((((p * 8 + kc) * 4 + ks) * 2 + mt) * 16 + col) * 4 + kg;
                f16x8 afr = *(const f16x8*)&waT[gidx];
                acc[p] = __builtin_amdgcn_mfma_f32_16x16x32_f16(afr, bfr, acc[p], 0, 0, 0);
            }
        }
        __syncthreads();
    }
#undef STAGE_LOAD
#undef STAGE_WRITE

    int px = y * 64 + xh * 32 + pxg * 16 + col;
    int ocl = mt * 16 + kg * 4;                 // first oc of this lane's 4
#pragma unroll
    for (int p = 0; p < 9; ++p) {
        __half* pc = part + ((size_t)((kh * 9 + p) * 2 + b)) * 28 * 4096 + px;
#pragma unroll
        for (int j = 0; j < 4; ++j)
            if (ocl + j < 28) pc[(size_t)(ocl + j) * 4096] = __float2half(acc[p][j]);
    }
}

// ---------------- K2: reduce 36 fp16 partials -> compact sampling meta ----------------
__global__ void k_meta(const __half* __restrict__ part, const float* __restrict__ b_off,
                       uint4* __restrict__ mu) {
    int idx = blockIdx.x * 256 + threadIdx.x;              // 2*9*4096
    if (idx >= 2 * 9 * 4096) return;
    int b = idx / (9 * 4096), r = idx % (9 * 4096), p = r / 4096, hw = r % 4096;
    int h = hw >> 6, w = hw & 63;
    float sdy = b_off[p], sdx = b_off[p + 9], sm = b_off[p + 18];
#pragma unroll 4
    for (int s = 0; s < 36; ++s) {
        const __half* pb = part + ((size_t)(s * 2 + b)) * 28 * 4096 + hw;
        sdy += __half2float(pb[(size_t)p * 4096]);
        sdx += __half2float(pb[(size_t)(p + 9) * 4096]);
        sm  += __half2float(pb[(size_t)(p + 18) * 4096]);
    }
    float m = 1.f / (1.f + expf(-sm));
    int ky = p / 3 - 1, kx = p % 3 - 1;
    float sy = (float)(h + ky) + sdy;
    float sx = (float)(w + kx) + sdx;
    float y0f = floorf(sy), x0f = floorf(sx);
    float wy = sy - y0f, wx = sx - x0f;
    int y0 = (int)fminf(fmaxf(y0f, -2.f), 64.f);
    int x0 = (int)fminf(fmaxf(x0f, -2.f), 64.f);
    bool vy0 = (y0 >= 0) && (y0 < 64), vy1 = (y0 + 1 >= 0) && (y0 + 1 < 64);
    bool vx0 = (x0 >= 0) && (x0 < 64), vx1 = (x0 + 1 >= 0) && (x0 + 1 < 64);
    float w00 = (1.f - wy) * (1.f - wx) * m * ((vy0 && vx0) ? 1.f : 0.f);
    float w01 = (1.f - wy) * wx         * m * ((vy0 && vx1) ? 1.f : 0.f);
    float w10 = wy * (1.f - wx)         * m * ((vy1 && vx0) ? 1.f : 0.f);
    float w11 = wy * wx                 * m * ((vy1 && vx1) ? 1.f : 0.f);
    int cy0 = min(max(y0, 0), 63),     cx0 = min(max(x0, 0), 63);
    int cy1 = min(max(y0 + 1, 0), 63), cx1 = min(max(x0 + 1, 0), 63);
    int blo = (h >> 3) * 8 - 6;
    blo = blo < 0 ? 0 : (blo > 44 ? 44 : blo);
    int blo64 = blo * 64;
    int s0 = cy0 * 64 + cx0 - blo64, s1 = cy0 * 64 + cx1 - blo64;
    int s2 = cy1 * 64 + cx0 - blo64, s3 = cy1 * 64 + cx1 - blo64;
    uint32_t wlo = (uint32_t)f2h(w00) | ((uint32_t)f2h(w01) << 16);
    uint32_t whi = (uint32_t)f2h(w10) | ((uint32_t)f2h(w11) << 16);
    uint32_t ilo = ((uint32_t)(uint16_t)(short)s0) | (((uint32_t)(uint16_t)(short)s1) << 16);
    uint32_t ihi = ((uint32_t)(uint16_t)(short)s2) | (((uint32_t)(uint16_t)(short)s3) << 16);
    mu[idx] = uint4{wlo, whi, ilo, ihi};
}

// ---------------- K3: deformable sample + grouped conv, LDS-staged texture ----------------
// Row-pair ILP: two rows' taps processed together -> 2 meta loads + 8 DS gathers in
// flight per step, shared A-fragments (half the weight loads). XCD g-swizzle + setprio kept.
__global__ __launch_bounds__(512, 4) void k_dcn_lds(const uint32_t* __restrict__ xt,
                                                    const uint32_t* __restrict__ wb,
                                                    const uint4* __restrict__ mu,
                                                    const float* __restrict__ b_dcn,
                                                    __half* __restrict__ hial) {
    __shared__ uint4 ldsq[5120];               // 20 rows * 64 px * 64 B = 80 KB
    int bx = blockIdx.x;
    int g = (bx & 7) * 4 + (bx >> 3);          // bijective XCD-locality swizzle
    int band = blockIdx.y, b = blockIdx.z;
    int y0 = band * 8;
    int band_lo = y0 - 6;
    if (band_lo < 0) band_lo = 0;
    if (band_lo > 44) band_lo = 44;
    int t = threadIdx.x;

    {
        const uint32_t* src = xt + ((size_t)(b * 8 + (g >> 2)) * 4096 + (size_t)band_lo * 64) * 64 + (g & 3) * 16;
#pragma unroll
        for (int i = 0; i < 10; ++i) {
            int Q = i * 512 + t;
            int s = Q >> 2;
            int q = (Q & 3) ^ ((s >> 1) & 3);
            ldsq[Q] = *(const uint4*)(src + (size_t)s * 64 + q * 4);
        }
    }
    __syncthreads();
    const uint32_t* ldsb = (const uint32_t*)ldsq;

    int wave = t >> 6, lane = t & 63;
    int col = lane & 15, kg = lane >> 4;
    int strip = (wave & 3) * 16;               // x-strip of 16 px
    int rbase = (wave >> 2) * 4;               // rows rbase..rbase+3 of the band
    const uint32_t* xb = xt + ((size_t)(b * 8 + (g >> 2)) * 4096) * 64 + (g & 3) * 16 + kg * 4;
    const uint32_t* wg = wb + (size_t)g * 9 * 32 * 16 + col * 16 + kg * 4;
    const uint4* mub = mu + (size_t)b * 9 * 4096;
    const float* bd  = b_dcn + g * 32;
    int blo64 = band_lo * 64;

#define LDSRD(SS) (*(const uint4*)(ldsb + (SS) * 16 + ((kg ^ (((SS) >> 1) & 3)) << 2)))
#define GSLOW(SS, U)                                                               \
    {                                                                              \
        int s_ = (SS);                                                             \
        int sc_ = s_ < 0 ? 0 : (s_ > 1279 ? 1279 : s_);                            \
        U = LDSRD(sc_);                                                            \
        if ((unsigned)s_ >= 1280u)                                                 \
            U = *(const uint4*)(xb + (size_t)(s_ + blo64) * 64);                   \
    }
// gather 4 corners for one meta word (fast LDS path / cold exact fallback)
#define TAPGATHER(CM, U0, U1, U2, U3)                                              \
    {                                                                              \
        int s0 = (short)((CM).z & 0xffffu), s1 = (short)((CM).z >> 16);            \
        int s2 = (short)((CM).w & 0xffffu), s3 = (short)((CM).w >> 16);            \
        unsigned mx = (unsigned)s0;                                                \
        mx = mx > (unsigned)s1 ? mx : (unsigned)s1;                                \
        mx = mx > (unsigned)s2 ? mx : (unsigned)s2;                                \
        mx = mx > (unsigned)s3 ? mx : (unsigned)s3;                                \
        if (__builtin_expect(mx >= 1280u, 0)) {                                    \
            GSLOW(s0, U0) GSLOW(s1, U1) GSLOW(s2, U2) GSLOW(s3, U3)                \
        } else {                                                                   \
            U0 = LDSRD(s0); U1 = LDSRD(s1); U2 = LDSRD(s2); U3 = LDSRD(s3);        \
        }                                                                          \
    }

#pragma unroll
    for (int rp = 0; rp < 2; ++rp) {
        int pixA = (y0 + rbase + 2 * rp) * 64 + strip + col;
        int pixB = pixA + 64;
        f32x4 a0A = {0.f, 0.f, 0.f, 0.f}, a1A = {0.f, 0.f, 0.f, 0.f};
        f32x4 a0B = {0.f, 0.f, 0.f, 0.f}, a1B = {0.f, 0.f, 0.f, 0.f};
#pragma unroll
        for (int p = 0; p < 9; ++p) {
            uint4 cmA = mub[p * 4096 + pixA];
            uint4 cmB = mub[p * 4096 + pixB];
            uint4 uA0, uA1, uA2, uA3, uB0, uB1, uB2, uB3;
            TAPGATHER(cmA, uA0, uA1, uA2, uA3)
            TAPGATHER(cmB, uB0, uB1, uB2, uB3)
            f16x8 bfrA = blend4h(uA0, uA1, uA2, uA3, u2h(cmA.x), u2h(cmA.y));
            f16x8 bfrB = blend4h(uB0, uB1, uB2, uB3, u2h(cmB.x), u2h(cmB.y));
            const uint32_t* ap = wg + (size_t)p * 512;
            f16x8 af0 = *(const f16x8*)ap;
            f16x8 af1 = *(const f16x8*)(ap + 256);
            __builtin_amdgcn_s_setprio(1);
            a0A = __builtin_amdgcn_mfma_f32_16x16x32_f16(af0, bfrA, a0A, 0, 0, 0);
            a1A = __builtin_amdgcn_mfma_f32_16x16x32_f16(af1, bfrA, a1A, 0, 0, 0);
            a0B = __builtin_amdgcn_mfma_f32_16x16x32_f16(af0, bfrB, a0B, 0, 0, 0);
            a1B = __builtin_amdgcn_mfma_f32_16x16x32_f16(af1, bfrB, a1B, 0, 0, 0);
            __builtin_amdgcn_s_setprio(0);
        }
        __half* pcA = hial + ((size_t)b * 1024 + g * 32) * 4096 + pixA;
        __half* pcB = pcA + 64;
#pragma unroll
        for (int j = 0; j < 4; ++j) {
            float b0 = bd[kg * 4 + j], b1 = bd[16 + kg * 4 + j];
            pcA[(size_t)(kg * 4 + j) * 4096]      = __float2half(a0A[j] + b0);
            pcA[(size_t)(16 + kg * 4 + j) * 4096] = __float2half(a1A[j] + b1);
            pcB[(size_t)(kg * 4 + j) * 4096]      = __float2half(a0B[j] + b0);
            pcB[(size_t)(16 + kg * 4 + j) * 4096] = __float2half(a1B[j] + b1);
        }
    }
#undef LDSRD
#undef GSLOW
#undef TAPGATHER
}

// ---------------- K4: fused upsample + grouped 1x1 conv (fp16 hial, NT stores) ----------------
__global__ __launch_bounds__(256, 4) void k_post5(const float* __restrict__ lo,
                                                  const __half* __restrict__ hial,
                                                  const float* __restrict__ wp,
                                                  const float* __restrict__ bp,
                                                  float* __restrict__ out) {
    int gq = blockIdx.x, kq = blockIdx.y, b = blockIdx.z;
    int t = threadIdx.x;
    int g = __builtin_amdgcn_readfirstlane(gq * 4 + (t >> 6));
    int lane = t & 63, k = kq * 4 + (lane >> 4), w4 = lane & 15;
    int rm = k > 0 ? k - 1 : 0, rp = k < 31 ? k + 1 : 31;
    int lc = 2 * w4 - 1; lc = lc < 0 ? 0 : (lc > 28 ? 28 : lc);
    bool is0 = (w4 == 0), is15 = (w4 == 15);

    f32x4 acc0[8], acc1[8];
#pragma unroll
    for (int o = 0; o < 8; ++o) {
        float bv = bp[g * 8 + o];
        acc0[o] = f32x4{bv, bv, bv, bv};
        acc1[o] = acc0[o];
    }
    const float* wrow = wp + (size_t)g * 96;
    int cbase = g * 12;

#define UPROW(LB, R, H)                                                            \
    {                                                                              \
        f32x4 q = *(const f32x4*)((LB) + (R) * 32 + lc);                           \
        float e0 = is15 ? q.y : q.x;                                               \
        float p0 = is0 ? q.x : (is15 ? q.z : q.y);                                 \
        float p1 = is0 ? q.y : (is15 ? q.w : q.z);                                 \
        float e3 = is0 ? q.z : q.w;                                                \
        H = f32x4{0.25f * e0 + 0.75f * p0, 0.75f * p0 + 0.25f * p1,                \
                  0.25f * p0 + 0.75f * p1, 0.75f * p1 + 0.25f * e3};               \
    }
#define LOCH(I)                                                                    \
    {                                                                              \
        const float* lb = lo + ((size_t)(b * 2048 + cbase + (I))) * 1024;          \
        f32x4 hm, hk, hp;                                                          \
        UPROW(lb, rm, hm) UPROW(lb, k, hk) UPROW(lb, rp, hp)                       \
        f32x4 va = 0.25f * hm + 0.75f * hk;                                        \
        f32x4 vb = 0.75f * hk + 0.25f * hp;                                        \
        _Pragma("unroll")                                                          \
        for (int o = 0; o < 8; ++o) {                                              \
            float w = wrow[o * 12 + (I)];                                          \
            acc0[o] += w * va;                                                     \
            acc1[o] += w * vb;                                                     \
        }                                                                          \
    }
#define HICH(I)                                                                    \
    {                                                                              \
        const __half* hb = hial + ((size_t)(b * 1024 + cbase + (I) - 2048)) * 4096 \
                          + (size_t)(2 * k) * 64 + 4 * w4;                         \
        __half2 ha0 = *(const __half2*)(hb);                                       \
        __half2 ha1 = *(const __half2*)(hb + 2);                                   \
        __half2 hb0 = *(const __half2*)(hb + 64);                                  \
        __half2 hb1 = *(const __half2*)(hb + 66);                                  \
        f32x4 va = {__half2float(ha0.x), __half2float(ha0.y),                      \
                    __half2float(ha1.x), __half2float(ha1.y)};                     \
        f32x4 vb = {__half2float(hb0.x), __half2float(hb0.y),                      \
                    __half2float(hb1.x), __half2float(hb1.y)};                     \
        _Pragma("unroll")                                                          \
        for (int o = 0; o < 8; ++o) {                                              \
            float w = wrow[o * 12 + (I)];                                          \
            acc0[o] += w * va;                                                     \
            acc1[o] += w * vb;                                                     \
        }                                                                          \
    }

    if (g <= 169) {
#pragma unroll 4
        for (int i = 0; i < 12; ++i) LOCH(i)
    } else if (g >= 171) {
#pragma unroll 4
        for (int i = 0; i < 12; ++i) HICH(i)
    } else {
#pragma unroll 4
        for (int i = 0; i < 8; ++i) LOCH(i)
#pragma unroll
        for (int i = 8; i < 12; ++i) HICH(i)
    }
#undef LOCH
#undef HICH
#undef UPROW

    float* ob = out + ((size_t)(b * 2048 + g * 8)) * 4096 + (size_t)(2 * k) * 64 + 4 * w4;
#pragma unroll
    for (int o = 0; o < 8; ++o) {
        __builtin_nontemporal_store(acc0[o], (f32x4*)(ob + (size_t)o * 4096));
        __builtin_nontemporal_store(acc1[o], (f32x4*)(ob + (size_t)o * 4096 + 64));
    }
}

extern "C" void kernel_launch(void* const* d_in, const int* in_sizes, int n_in,
                              void* d_out, int out_size, void* d_ws, size_t ws_size,
                              hipStream_t stream) {
    const float* lo_res = (const float*)d_in[0];
    const float* hi_res = (const float*)d_in[1];
    const float* w_off  = (const float*)d_in[2];
    const float* b_off  = (const float*)d_in[3];
    const float* w_dcn  = (const float*)d_in[4];
    const float* b_dcn  = (const float*)d_in[5];
    const float* w_post = (const float*)d_in[6];
    const float* b_post = (const float*)d_in[7];
    float* out = (float*)d_out;
    char* ws = (char*)d_ws;

    uint32_t* xt  = (uint32_t*)(ws + OFF_XT);
    __half* hial  = (__half*)(ws + OFF_HIAL);
    __half* part  = (__half*)(ws + OFF_PART);    // aliases hial region (consumed before hial written)
    uint4* mup    = (uint4*)(ws + OFF_MU);
    uint4* waT    = (uint4*)(ws + OFF_WA);
    uint32_t* wbp = (uint32_t*)(ws + OFF_WB);

    k_prep<<<(36864 + 32 * 9 * 32 * 16 + 255) / 256, 256, 0, stream>>>(w_off, w_dcn, waT, wbp);
    k_transpose<<<dim3(16, 64, 2), 256, 0, stream>>>(hi_res, xt);
    k_offconv_mfma<<<dim3(128, 4, 2), 256, 0, stream>>>(xt, waT, part);
    k_meta<<<(2 * 9 * 4096 + 255) / 256, 256, 0, stream>>>(part, b_off, mup);
    k_dcn_lds<<<dim3(32, 8, 2), 512, 0, stream>>>(xt, wbp, mup, b_dcn, hial);
    k_post5<<<dim3(64, 8, 2), 256, 0, stream>>>(lo_res, hial, w_post, b_post, out);
}